// Round 8
// baseline (283.974 us; speedup 1.0000x reference)
//
#include <hip/hip_runtime.h>
#include <hip/hip_bf16.h>
#include <hip/hip_cooperative_groups.h>

namespace cg = cooperative_groups;

#define NVOX 4096
#define C    128
#define HID  512
#define EPSF 1e-6f

typedef __attribute__((ext_vector_type(8))) short bf16x8;
typedef __attribute__((ext_vector_type(4))) float f32x4;

__device__ __forceinline__ short f2bs(float f) {
    __hip_bfloat16 h = __float2bfloat16(f);
    short s; __builtin_memcpy(&s, &h, 2); return s;
}
__device__ __forceinline__ float bs2f(unsigned short u) {
    return __uint_as_float(((unsigned)u) << 16);
}

// A-frag from swizzled LDS tile hs[16][128] (bf16 shorts, col ^ ((row&7)<<3))
__device__ __forceinline__ bf16x8 lda(const short* hs, int lane, int ks) {
    int r = lane & 15, g = lane >> 4;
    int col = (ks * 32 + g * 8) ^ ((r & 7) << 3);
    return *(const bf16x8*)(hs + r * 128 + col);
}

// ---------------- cooperative mega-kernel: prep | qkv | attn | post ----------------
__global__ void __launch_bounds__(512) k_mega(
    const float* __restrict__ x,  const float* __restrict__ n1,
    const float* __restrict__ anw, const float* __restrict__ n2w,
    const float* __restrict__ wq, const float* __restrict__ wk,
    const float* __restrict__ wv, const float* __restrict__ wo,
    const float* __restrict__ gw, const float* __restrict__ uw,
    const float* __restrict__ dw, float* __restrict__ out,
    float* __restrict__ qf, short* __restrict__ kbf,
    short* __restrict__ vbf, short* __restrict__ obf,
    short* __restrict__ wsw)
{
    cg::grid_group grid = cg::this_grid();
    __shared__ __align__(16) char smem[122880];
    __shared__ int tab[125];
    const int t = threadIdx.x;
    const int bid = blockIdx.x;

    // ================= phase 0: weight prep (fp32 -> bf16 fragment order) ======
    #pragma unroll
    for (int e = 0; e < 2; e++) {
        int id = bid * 1024 + e * 512 + t;   // 262144 total
        const float* src; int base, k, c, N, K;
        if (id < 65536) {
            int m = id >> 14, loc = id & 16383;
            src = (m == 0) ? wq : (m == 1) ? wk : (m == 2) ? wv : wo;
            base = m << 14; N = 128; K = 128;
            k = loc >> 7; c = loc & 127;
        } else {
            int l2 = id - 65536, m = l2 >> 16, loc = l2 & 65535;
            if (m == 0)      { src = gw; base = 65536;  N = 512; K = 128; }
            else if (m == 1) { src = uw; base = 131072; N = 512; K = 128; }
            else             { src = dw; base = 196608; N = 128; K = 512; }
            k = (N == 512) ? (loc >> 9) : (loc >> 7);
            c = (N == 512) ? (loc & 511) : (loc & 127);
        }
        int KS = K >> 5;
        int ct = c >> 4, ks = k >> 5, lane = ((k >> 3) & 3) * 16 + (c & 15), j = k & 7;
        wsw[base + (((ct * KS + ks) * 64 + lane) << 3) + j] = f2bs(src[k * N + c]);
    }
    __threadfence();
    grid.sync();

    // ================= phase 1: rmsnorm(x)*n1 -> q(f32), k(bf16), v(bf16) ======
    {
        float (*xs)[128] = (float(*)[128])smem;            // 8192 B
        short* hs        = (short*)(smem + 8192);          // 4096 B
        float (*red)[8]  = (float(*)[8])(smem + 12288);    // 512 B
        float* scl       = (float*)(smem + 12800);         // 64 B
        const int r0 = bid * 16;

        {
            int r = t >> 5, jc = (t & 31) << 2;
            *(float4*)&xs[r][jc] = *(const float4*)&x[(size_t)(r0 + r) * 128 + jc];
        }
        __syncthreads();
        if (t < 128) {
            int r = t >> 3, seg = t & 7; float s = 0.f;
            #pragma unroll
            for (int i = 0; i < 16; i++) { float xv = xs[r][seg * 16 + i]; s = fmaf(xv, xv, s); }
            red[r][seg] = s;
        }
        __syncthreads();
        if (t < 16) {
            float s = 0.f;
            #pragma unroll
            for (int i = 0; i < 8; i++) s += red[t][i];
            scl[t] = rsqrtf(s * (1.0f / 128.0f) + EPSF);
        }
        __syncthreads();
        for (int vi = t; vi < 2048; vi += 512) {
            int r = vi >> 7, c = vi & 127;
            hs[r * 128 + (c ^ ((r & 7) << 3))] = f2bs(xs[r][c] * scl[r] * n1[c]);
        }
        __syncthreads();

        const int w = t >> 6, lane = t & 63;
        bf16x8 af[4];
        #pragma unroll
        for (int ks = 0; ks < 4; ks++) af[ks] = lda(hs, lane, ks);

        const int rb = (lane >> 4) * 4, cl = lane & 15;
        #pragma unroll
        for (int i = 0; i < 3; i++) {
            int gt = w * 3 + i;            // 24 col-tiles over [q|k|v]
            int m = gt >> 3, ct = gt & 7;
            const short* wb = wsw + (m << 14);
            f32x4 a0 = {0.f,0.f,0.f,0.f};
            #pragma unroll
            for (int ks = 0; ks < 4; ks++) {
                bf16x8 b0 = *(const bf16x8*)(wb + (((ct * 4 + ks) * 64 + lane) << 3));
                a0 = __builtin_amdgcn_mfma_f32_16x16x32_bf16(af[ks], b0, a0, 0, 0, 0);
            }
            if (m == 0) {
                #pragma unroll
                for (int j = 0; j < 4; j++)
                    qf[(size_t)(r0 + rb + j) * 128 + ct * 16 + cl] = a0[j];
            } else {
                short* outp = (m == 1) ? kbf : vbf;
                #pragma unroll
                for (int j = 0; j < 4; j++)
                    outp[(size_t)(r0 + rb + j) * 128 + ct * 16 + cl] = f2bs(a0[j]);
            }
        }
    }
    __threadfence();
    grid.sync();

    // ================= phase 2: brick attention (2 units x 256 thr) ============
    {
        const int tu = t & 255;
        const int u  = t >> 8;
        const int brick = bid >> 1;
        const int head = ((bid & 1) << 1) | u;
        short* K_lds = (short*)(smem + u * 61440);
        short* V_lds = (short*)(smem + u * 61440 + 30720);
        const int ow = (brick & 3) * 4, oh = ((brick >> 2) & 3) * 4, od = (brick >> 4) * 2;

        if (t < 125) {
            int dd = t / 25, rem = t % 25;
            tab[t] = dd | ((rem / 5) << 4) | ((rem % 5) << 8);
        }
        for (int row = tu; row < 384; row += 256) {
            int lw = row & 7, lh = (row >> 3) & 7, ld = row >> 6;
            int gd = od - 2 + ld, gh = oh - 2 + lh, gw_ = ow - 2 + lw;
            uint4 kc[4], vc[4];
            if (((unsigned)gd < 16u) && ((unsigned)gh < 16u) && ((unsigned)gw_ < 16u)) {
                size_t off = ((size_t)(((gd << 4) | gh) << 4 | gw_)) * 128 + head * 32;
                #pragma unroll
                for (int c2 = 0; c2 < 4; c2++) {
                    kc[c2] = *(const uint4*)(kbf + off + c2 * 8);
                    vc[c2] = *(const uint4*)(vbf + off + c2 * 8);
                }
            } else {
                #pragma unroll
                for (int c2 = 0; c2 < 4; c2++) { kc[c2] = (uint4){0,0,0,0}; vc[c2] = (uint4){0,0,0,0}; }
            }
            #pragma unroll
            for (int c2 = 0; c2 < 4; c2++) {
                *(uint4*)&K_lds[row * 40 + c2 * 8] = kc[c2];
                *(uint4*)&V_lds[row * 40 + c2 * 8] = vc[c2];
            }
        }
        __syncthreads();

        const int qi = tu >> 3, qt = tu & 7;     // 32 queries x 8 lanes
        const int qw_ = qi & 3, qh_ = (qi >> 2) & 3, qd_ = qi >> 4;
        const int gqd = od + qd_, gqh = oh + qh_, gqw = ow + qw_;
        const int gvox = (((gqd << 4) | gqh) << 4) | gqw;
        const int base = (qd_ + 2) * 64 + (qh_ + 2) * 8 + (qw_ + 2);

        float qreg[32];
        {
            const float isq = 0.17677669529663687f;   // 1/sqrt(32)
            const float* qp = qf + (size_t)gvox * 128 + head * 32;
            #pragma unroll
            for (int c2 = 0; c2 < 8; c2++) {
                float4 f = *(const float4*)(qp + c2 * 4);
                qreg[c2 * 4 + 0] = f.x * isq; qreg[c2 * 4 + 1] = f.y * isq;
                qreg[c2 * 4 + 2] = f.z * isq; qreg[c2 * 4 + 3] = f.w * isq;
            }
        }

        float sc[16]; int hid[16];
        float m = -1e30f;
        const int kk0 = qt * 16;
        #pragma unroll
        for (int i = 0; i < 16; i++) {
            int kk = kk0 + i;
            float s = -1e30f; int h = 0;
            if (kk < 125) {
                int tt = tab[kk];
                int dd = (tt & 15) - 2, dh = ((tt >> 4) & 15) - 2, dw_ = (tt >> 8) - 2;
                if (((unsigned)(gqd + dd) < 16u) & ((unsigned)(gqh + dh) < 16u) & ((unsigned)(gqw + dw_) < 16u)) {
                    h = base + dd * 64 + dh * 8 + dw_;
                    float acc = 0.f;
                    #pragma unroll
                    for (int c2 = 0; c2 < 4; c2++) {
                        uint4 raw = *(const uint4*)&K_lds[h * 40 + c2 * 8];
                        const unsigned short* uu = (const unsigned short*)&raw;
                        #pragma unroll
                        for (int j = 0; j < 8; j++) acc = fmaf(qreg[c2 * 8 + j], bs2f(uu[j]), acc);
                    }
                    s = acc;
                }
            }
            sc[i] = s; hid[i] = h;
            m = fmaxf(m, s);
        }
        m = fmaxf(m, __shfl_xor(m, 1));
        m = fmaxf(m, __shfl_xor(m, 2));
        m = fmaxf(m, __shfl_xor(m, 4));
        float ssum = 0.f;
        #pragma unroll
        for (int i = 0; i < 16; i++) {
            float p = (sc[i] > -1e29f) ? __expf(sc[i] - m) : 0.f;
            sc[i] = p; ssum += p;
        }
        ssum += __shfl_xor(ssum, 1);
        ssum += __shfl_xor(ssum, 2);
        ssum += __shfl_xor(ssum, 4);
        const float inv = 1.0f / ssum;

        float acc[32];
        #pragma unroll
        for (int c2 = 0; c2 < 32; c2++) acc[c2] = 0.f;
        #pragma unroll
        for (int i = 0; i < 16; i++) {
            float p = sc[i]; int h = hid[i];
            #pragma unroll
            for (int c2 = 0; c2 < 4; c2++) {
                uint4 raw = *(const uint4*)&V_lds[h * 40 + c2 * 8];
                const unsigned short* uu = (const unsigned short*)&raw;
                #pragma unroll
                for (int j = 0; j < 8; j++) acc[c2 * 8 + j] = fmaf(p, bs2f(uu[j]), acc[c2 * 8 + j]);
            }
        }
        #pragma unroll
        for (int c2 = 0; c2 < 32; c2++) {
            acc[c2] += __shfl_xor(acc[c2], 1);
            acc[c2] += __shfl_xor(acc[c2], 2);
            acc[c2] += __shfl_xor(acc[c2], 4);
        }
        short o4[4];
        #pragma unroll
        for (int j = 0; j < 4; j++) o4[j] = f2bs(acc[qt * 4 + j] * inv);
        unsigned long long pk; __builtin_memcpy(&pk, o4, 8);
        *(unsigned long long*)&obf[(size_t)gvox * 128 + head * 32 + qt * 4] = pk;
    }
    __threadfence();
    grid.sync();

    // ================= phase 3: attnout + ffn1 + ffn2 (LDS-resident) ===========
    {
        float (*ybuf)[132] = (float(*)[132])smem;                // 8448 B
        float (*xres)[128] = (float(*)[128])(smem + 8448);       // 8192 B
        short* hs          = (short*)(smem + 16640);             // 4096 B
        short* gu          = (short*)(smem + 20736);             // 16384 B
        float (*red)[8]    = (float(*)[8])(smem + 37120);        // 512 B
        float* scl         = (float*)(smem + 37632);             // 64 B

        const int r0 = bid * 16;
        const int w = t >> 6, lane = t & 63;
        const int ar = lane & 15, ag_ = lane >> 4;

        // y = o @ wo  (8 waves x 16-col tile)
        {
            const short* wb = wsw + (3 << 14);
            f32x4 a0 = {0.f,0.f,0.f,0.f};
            #pragma unroll
            for (int ks = 0; ks < 4; ks++) {
                bf16x8 a = *(const bf16x8*)(obf + (size_t)(r0 + ar) * 128 + ks * 32 + ag_ * 8);
                bf16x8 b0 = *(const bf16x8*)(wb + (((w * 4 + ks) * 64 + lane) << 3));
                a0 = __builtin_amdgcn_mfma_f32_16x16x32_bf16(a, b0, a0, 0, 0, 0);
            }
            #pragma unroll
            for (int i = 0; i < 4; i++)
                ybuf[ag_ * 4 + i][w * 16 + ar] = a0[i];
        }
        __syncthreads();

        // xres = x + rmsnorm(y)*anw
        if (t < 128) {
            int r = t >> 3, seg = t & 7; float s = 0.f;
            #pragma unroll
            for (int i = 0; i < 16; i++) { float yv = ybuf[r][seg * 16 + i]; s = fmaf(yv, yv, s); }
            red[r][seg] = s;
        }
        __syncthreads();
        if (t < 16) {
            float s = 0.f;
            #pragma unroll
            for (int i = 0; i < 8; i++) s += red[t][i];
            scl[t] = rsqrtf(s * (1.0f / 128.0f) + EPSF);
        }
        __syncthreads();
        {
            int r = t >> 5, jc = (t & 31) << 2;
            float4 xv = *(const float4*)&x[(size_t)(r0 + r) * 128 + jc];
            float4 aw = *(const float4*)&anw[jc];
            float sc2 = scl[r];
            float4 o;
            o.x = xv.x + ybuf[r][jc + 0] * sc2 * aw.x;
            o.y = xv.y + ybuf[r][jc + 1] * sc2 * aw.y;
            o.z = xv.z + ybuf[r][jc + 2] * sc2 * aw.z;
            o.w = xv.w + ybuf[r][jc + 3] * sc2 * aw.w;
            *(float4*)&xres[r][jc] = o;
        }
        __syncthreads();

        // h2 = rmsnorm(xres)*n2w -> hs (swizzled bf16)
        if (t < 128) {
            int r = t >> 3, seg = t & 7; float s = 0.f;
            #pragma unroll
            for (int i = 0; i < 16; i++) { float xv = xres[r][seg * 16 + i]; s = fmaf(xv, xv, s); }
            red[r][seg] = s;
        }
        __syncthreads();
        if (t < 16) {
            float s = 0.f;
            #pragma unroll
            for (int i = 0; i < 8; i++) s += red[t][i];
            scl[t] = rsqrtf(s * (1.0f / 128.0f) + EPSF);
        }
        __syncthreads();
        for (int vi = t; vi < 2048; vi += 512) {
            int r = vi >> 7, c = vi & 127;
            hs[r * 128 + (c ^ ((r & 7) << 3))] = f2bs(xres[r][c] * scl[r] * n2w[c]);
        }
        __syncthreads();

        // gu = silu(h2@gw)*(h2@uw)  (8 waves x 4 col-tiles)
        {
            const short* gwb = wsw + 65536;
            const short* uwb = wsw + 131072;
            bf16x8 af[4];
            #pragma unroll
            for (int ks = 0; ks < 4; ks++) af[ks] = lda(hs, lane, ks);
            f32x4 ag[4], au[4];
            #pragma unroll
            for (int i = 0; i < 4; i++) { ag[i] = (f32x4){0.f,0.f,0.f,0.f}; au[i] = (f32x4){0.f,0.f,0.f,0.f}; }
            #pragma unroll
            for (int ks = 0; ks < 4; ks++) {
                #pragma unroll
                for (int i = 0; i < 4; i++) {
                    int ct = w * 4 + i;
                    bf16x8 bg = *(const bf16x8*)(gwb + (((ct * 4 + ks) * 64 + lane) << 3));
                    bf16x8 bu = *(const bf16x8*)(uwb + (((ct * 4 + ks) * 64 + lane) << 3));
                    ag[i] = __builtin_amdgcn_mfma_f32_16x16x32_bf16(af[ks], bg, ag[i], 0, 0, 0);
                    au[i] = __builtin_amdgcn_mfma_f32_16x16x32_bf16(af[ks], bu, au[i], 0, 0, 0);
                }
            }
            #pragma unroll
            for (int i = 0; i < 4; i++) {
                int col = (w * 4 + i) * 16 + ar;
                #pragma unroll
                for (int j = 0; j < 4; j++) {
                    int row = ag_ * 4 + j;
                    float g = ag[i][j], uu = au[i][j];
                    float sg = g / (1.0f + __expf(-g));
                    gu[row * 512 + (col ^ ((row & 7) << 3))] = f2bs(sg * uu);
                }
            }
        }
        __syncthreads();

        // out = xres + gu @ dw  (8 waves x 16-col tile, K=512)
        {
            const short* db = wsw + 196608;
            f32x4 a0 = {0.f,0.f,0.f,0.f};
            #pragma unroll
            for (int ks = 0; ks < 16; ks++) {
                int col = (ks * 32 + ag_ * 8) ^ ((ar & 7) << 3);
                bf16x8 a = *(const bf16x8*)(gu + ar * 512 + col);
                bf16x8 b0 = *(const bf16x8*)(db + (((w * 16 + ks) * 64 + lane) << 3));
                a0 = __builtin_amdgcn_mfma_f32_16x16x32_bf16(a, b0, a0, 0, 0, 0);
            }
            #pragma unroll
            for (int i = 0; i < 4; i++) {
                int row = ag_ * 4 + i;
                size_t i0 = (size_t)(r0 + row) * 128 + w * 16 + ar;
                out[i0] = xres[row][w * 16 + ar] + a0[i];
            }
        }
    }
}

extern "C" void kernel_launch(void* const* d_in, const int* in_sizes, int n_in,
                              void* d_out, int out_size, void* d_ws, size_t ws_size,
                              hipStream_t stream)
{
    const float* x   = (const float*)d_in[0];
    const float* n1  = (const float*)d_in[1];
    const float* anw = (const float*)d_in[2];
    const float* n2  = (const float*)d_in[3];
    const float* wq  = (const float*)d_in[4];
    const float* wk  = (const float*)d_in[5];
    const float* wv  = (const float*)d_in[6];
    const float* wo  = (const float*)d_in[7];
    const float* gw  = (const float*)d_in[8];
    const float* uw  = (const float*)d_in[9];
    const float* dw  = (const float*)d_in[10];
    float* out = (float*)d_out;

    float* ws = (float*)d_ws;
    float* qf   = ws;                         // 524288 f
    short* kbf  = (short*)(ws + 524288);
    short* vbf  = (short*)(ws + 786432);
    short* obf  = (short*)(ws + 1048576);
    short* wsw  = (short*)(ws + 1310720);

    void* args[] = {
        (void*)&x, (void*)&n1, (void*)&anw, (void*)&n2,
        (void*)&wq, (void*)&wk, (void*)&wv, (void*)&wo,
        (void*)&gw, (void*)&uw, (void*)&dw, (void*)&out,
        (void*)&qf, (void*)&kbf, (void*)&vbf, (void*)&obf, (void*)&wsw
    };
    hipLaunchCooperativeKernel((void*)k_mega, dim3(256), dim3(512), args, 0, stream);
}

// Round 9
// 42.014 us; speedup vs baseline: 6.7590x; 6.7590x over previous
//
#include <hip/hip_runtime.h>
#include <hip/hip_bf16.h>

#define NVOX 4096
#define C    128
#define HID  512
#define EPSF 1e-6f

typedef __attribute__((ext_vector_type(8))) short bf16x8;
typedef __attribute__((ext_vector_type(4))) float f32x4;

__device__ __forceinline__ short f2bs(float f) {
    __hip_bfloat16 h = __float2bfloat16(f);
    short s; __builtin_memcpy(&s, &h, 2); return s;
}
__device__ __forceinline__ float bs2f(unsigned short u) {
    return __uint_as_float(((unsigned)u) << 16);
}

// A-frag from swizzled LDS tile hs[16][128] (bf16 shorts, col ^ ((row&7)<<3))
__device__ __forceinline__ bf16x8 lda(const short* hs, int lane, int ks) {
    int r = lane & 15, g = lane >> 4;
    int col = (ks * 32 + g * 8) ^ ((r & 7) << 3);
    return *(const bf16x8*)(hs + r * 128 + col);
}

__device__ __forceinline__ float wave_rsum(float s) {
    s += __shfl_xor(s, 32); s += __shfl_xor(s, 16); s += __shfl_xor(s, 8);
    s += __shfl_xor(s, 4);  s += __shfl_xor(s, 2);  s += __shfl_xor(s, 1);
    return s;
}

// ---------- weight prep: fp32 -> bf16 fragment-order, coalesced bf16x8 stores ----------
// 32768 threads; each handles 8 consecutive k (one dst bf16x8).
__global__ __launch_bounds__(512) void k_prep(
    const float* __restrict__ wq, const float* __restrict__ wk,
    const float* __restrict__ wv, const float* __restrict__ wo,
    const float* __restrict__ gw, const float* __restrict__ uw,
    const float* __restrict__ dw, short* __restrict__ wsw)
{
    int id = blockIdx.x * 512 + threadIdx.x;   // [0, 32768)
    const float* src; int base, ct, ks, lane, N, KS;
    if (id < 8192) {                       // wq/wk/wv/wo: 128x128, 2048 thr each
        int m = id >> 11, loc = id & 2047;
        src = (m == 0) ? wq : (m == 1) ? wk : (m == 2) ? wv : wo;
        base = m << 14; N = 128; KS = 4;
        ct = loc >> 8; ks = (loc >> 6) & 3; lane = loc & 63;
    } else if (id < 16384) {               // gw: 128x512
        int loc = id - 8192;
        src = gw; base = 65536; N = 512; KS = 4;
        ct = loc >> 8; ks = (loc >> 6) & 3; lane = loc & 63;
    } else if (id < 24576) {               // uw: 128x512
        int loc = id - 16384;
        src = uw; base = 131072; N = 512; KS = 4;
        ct = loc >> 8; ks = (loc >> 6) & 3; lane = loc & 63;
    } else {                               // dw: 512x128
        int loc = id - 24576;
        src = dw; base = 196608; N = 128; KS = 16;
        ct = loc >> 10; ks = (loc >> 6) & 15; lane = loc & 63;
    }
    int k0 = ks * 32 + (lane >> 4) * 8;
    int c  = ct * 16 + (lane & 15);
    bf16x8 v;
    #pragma unroll
    for (int j = 0; j < 8; j++) v[j] = f2bs(src[(size_t)(k0 + j) * N + c]);
    *(bf16x8*)(wsw + base + (((ct * KS + ks) * 64 + lane) << 3)) = v;
}

// ---------- K1: rmsnorm(x)*n1 -> q(bf16), k(bf16), v(bf16); 256 thr ----------
__global__ __launch_bounds__(256) void k_qkv(
    const float* __restrict__ x, const float* __restrict__ n1,
    const short* __restrict__ wsw,
    short* __restrict__ qbf, short* __restrict__ kbf, short* __restrict__ vbf)
{
    __shared__ short hs[2048];
    const int r0 = blockIdx.x * 16, t = threadIdx.x;
    const int w = t >> 6, lane = t & 63;

    // per-wave rmsnorm: wave w owns rows 4w..4w+3 (no block barriers)
    #pragma unroll
    for (int i = 0; i < 4; i++) {
        int r = w * 4 + i;
        const float* xp = x + (size_t)(r0 + r) * 128;
        float v0 = xp[lane], v1 = xp[lane + 64];
        float s = wave_rsum(fmaf(v0, v0, v1 * v1));
        float sc = rsqrtf(s * (1.0f / 128.0f) + EPSF);
        int p3 = (r & 7) << 3;
        hs[r * 128 + (lane ^ p3)]        = f2bs(v0 * sc * n1[lane]);
        hs[r * 128 + ((lane + 64) ^ p3)] = f2bs(v1 * sc * n1[lane + 64]);
    }
    __syncthreads();

    bf16x8 af[4];
    #pragma unroll
    for (int ks = 0; ks < 4; ks++) af[ks] = lda(hs, lane, ks);

    const int rb = (lane >> 4) * 4, cl = lane & 15, cb = w * 32;
    #pragma unroll
    for (int m = 0; m < 3; m++) {
        const short* wb = wsw + (m << 14);
        f32x4 a0 = {0.f,0.f,0.f,0.f}, a1 = {0.f,0.f,0.f,0.f};
        #pragma unroll
        for (int ks = 0; ks < 4; ks++) {
            bf16x8 b0 = *(const bf16x8*)(wb + ((((w * 2) * 4 + ks) * 64 + lane) << 3));
            bf16x8 b1 = *(const bf16x8*)(wb + ((((w * 2 + 1) * 4 + ks) * 64 + lane) << 3));
            a0 = __builtin_amdgcn_mfma_f32_16x16x32_bf16(af[ks], b0, a0, 0, 0, 0);
            a1 = __builtin_amdgcn_mfma_f32_16x16x32_bf16(af[ks], b1, a1, 0, 0, 0);
        }
        short* outp = (m == 0) ? qbf : (m == 1) ? kbf : vbf;
        #pragma unroll
        for (int i = 0; i < 4; i++) {
            outp[(size_t)(r0 + rb + i) * 128 + cb + cl]      = f2bs(a0[i]);
            outp[(size_t)(r0 + rb + i) * 128 + cb + 16 + cl] = f2bs(a1[i]);
        }
    }
}

// ---------- K2: brick-tiled local attention (round-6 proven layout, bf16 q) ----------
__global__ __launch_bounds__(256) void k_attn(
    const short* __restrict__ qbf, const short* __restrict__ kbf,
    const short* __restrict__ vbf, short* __restrict__ obf)
{
    __shared__ short K_lds[384 * 40];
    __shared__ short V_lds[384 * 40];
    __shared__ int tab[125];

    const int b = blockIdx.x, head = blockIdx.y, t = threadIdx.x;
    const int ow = (b & 3) * 4, oh = ((b >> 2) & 3) * 4, od = (b >> 4) * 2;

    if (t < 125) {
        int dd = t / 25, rem = t % 25;
        tab[t] = dd | ((rem / 5) << 4) | ((rem % 5) << 8);
    }
    for (int row = t; row < 384; row += 256) {
        int lw = row & 7, lh = (row >> 3) & 7, ld = row >> 6;
        int gd = od - 2 + ld, gh = oh - 2 + lh, gw_ = ow - 2 + lw;
        uint4 kc[4], vc[4];
        if (((unsigned)gd < 16u) && ((unsigned)gh < 16u) && ((unsigned)gw_ < 16u)) {
            size_t off = ((size_t)(((gd << 4) | gh) << 4 | gw_)) * 128 + head * 32;
            #pragma unroll
            for (int c2 = 0; c2 < 4; c2++) {
                kc[c2] = *(const uint4*)(kbf + off + c2 * 8);
                vc[c2] = *(const uint4*)(vbf + off + c2 * 8);
            }
        } else {
            #pragma unroll
            for (int c2 = 0; c2 < 4; c2++) { kc[c2] = (uint4){0,0,0,0}; vc[c2] = (uint4){0,0,0,0}; }
        }
        #pragma unroll
        for (int c2 = 0; c2 < 4; c2++) {
            *(uint4*)&K_lds[row * 40 + c2 * 8] = kc[c2];
            *(uint4*)&V_lds[row * 40 + c2 * 8] = vc[c2];
        }
    }
    __syncthreads();

    const int qi = t >> 3, qt = t & 7;           // 32 queries x 8 lanes
    const int qw_ = qi & 3, qh_ = (qi >> 2) & 3, qd_ = qi >> 4;
    const int gqd = od + qd_, gqh = oh + qh_, gqw = ow + qw_;
    const int gvox = (((gqd << 4) | gqh) << 4) | gqw;
    const int base = (qd_ + 2) * 64 + (qh_ + 2) * 8 + (qw_ + 2);

    float qreg[32];
    {
        const float isq = 0.17677669529663687f;  // 1/sqrt(32)
        const short* qp = qbf + (size_t)gvox * 128 + head * 32;
        #pragma unroll
        for (int c2 = 0; c2 < 4; c2++) {
            uint4 raw = *(const uint4*)(qp + c2 * 8);
            const unsigned short* u = (const unsigned short*)&raw;
            #pragma unroll
            for (int j = 0; j < 8; j++) qreg[c2 * 8 + j] = bs2f(u[j]) * isq;
        }
    }

    float sc[16]; int hid[16];
    float m = -1e30f;
    const int kk0 = qt * 16;
    #pragma unroll
    for (int i = 0; i < 16; i++) {
        int kk = kk0 + i;
        float s = -1e30f; int h = 0;
        if (kk < 125) {
            int tt = tab[kk];
            int dd = (tt & 15) - 2, dh = ((tt >> 4) & 15) - 2, dw_ = (tt >> 8) - 2;
            if (((unsigned)(gqd + dd) < 16u) & ((unsigned)(gqh + dh) < 16u) & ((unsigned)(gqw + dw_) < 16u)) {
                h = base + dd * 64 + dh * 8 + dw_;
                float acc = 0.f;
                #pragma unroll
                for (int c2 = 0; c2 < 4; c2++) {
                    uint4 raw = *(const uint4*)&K_lds[h * 40 + c2 * 8];
                    const unsigned short* u = (const unsigned short*)&raw;
                    #pragma unroll
                    for (int j = 0; j < 8; j++) acc = fmaf(qreg[c2 * 8 + j], bs2f(u[j]), acc);
                }
                s = acc;
            }
        }
        sc[i] = s; hid[i] = h;
        m = fmaxf(m, s);
    }
    m = fmaxf(m, __shfl_xor(m, 1));
    m = fmaxf(m, __shfl_xor(m, 2));
    m = fmaxf(m, __shfl_xor(m, 4));
    float ssum = 0.f;
    #pragma unroll
    for (int i = 0; i < 16; i++) {
        float p = (sc[i] > -1e29f) ? __expf(sc[i] - m) : 0.f;
        sc[i] = p; ssum += p;
    }
    ssum += __shfl_xor(ssum, 1);
    ssum += __shfl_xor(ssum, 2);
    ssum += __shfl_xor(ssum, 4);
    const float inv = 1.0f / ssum;

    float acc[32];
    #pragma unroll
    for (int c2 = 0; c2 < 32; c2++) acc[c2] = 0.f;
    #pragma unroll
    for (int i = 0; i < 16; i++) {
        float p = sc[i]; int h = hid[i];
        #pragma unroll
        for (int c2 = 0; c2 < 4; c2++) {
            uint4 raw = *(const uint4*)&V_lds[h * 40 + c2 * 8];
            const unsigned short* u = (const unsigned short*)&raw;
            #pragma unroll
            for (int j = 0; j < 8; j++) acc[c2 * 8 + j] = fmaf(p, bs2f(u[j]), acc[c2 * 8 + j]);
        }
    }
    #pragma unroll
    for (int c2 = 0; c2 < 32; c2++) {
        acc[c2] += __shfl_xor(acc[c2], 1);
        acc[c2] += __shfl_xor(acc[c2], 2);
        acc[c2] += __shfl_xor(acc[c2], 4);
    }
    short o4[4];
    #pragma unroll
    for (int j = 0; j < 4; j++) o4[j] = f2bs(acc[qt * 4 + j] * inv);
    unsigned long long pk; __builtin_memcpy(&pk, o4, 8);
    *(unsigned long long*)&obf[(size_t)gvox * 128 + head * 32 + qt * 4] = pk;
}

// ---------- K3: fused post-chain, 3 barriers (per-wave rmsnorms) ----------
__global__ __launch_bounds__(256) void k_post(
    const short* __restrict__ obf, const short* __restrict__ wsw,
    const float* __restrict__ anw, const float* __restrict__ x,
    const float* __restrict__ n2w, float* __restrict__ out)
{
    __shared__ float ybuf[16][132];
    __shared__ float xres[16][128];
    __shared__ short hs[2048];
    __shared__ short gu[16 * 512];

    const int r0 = blockIdx.x * 16, t = threadIdx.x;
    const int w = t >> 6, lane = t & 63;
    const int ar = lane & 15, ag_ = lane >> 4;

    // phase 1: y = o @ wo
    {
        const short* wb = wsw + (3 << 14);
        f32x4 a0 = {0.f,0.f,0.f,0.f}, a1 = {0.f,0.f,0.f,0.f};
        #pragma unroll
        for (int ks = 0; ks < 4; ks++) {
            bf16x8 a = *(const bf16x8*)(obf + (size_t)(r0 + ar) * 128 + ks * 32 + ag_ * 8);
            bf16x8 b0 = *(const bf16x8*)(wb + ((((w * 2) * 4 + ks) * 64 + lane) << 3));
            bf16x8 b1 = *(const bf16x8*)(wb + ((((w * 2 + 1) * 4 + ks) * 64 + lane) << 3));
            a0 = __builtin_amdgcn_mfma_f32_16x16x32_bf16(a, b0, a0, 0, 0, 0);
            a1 = __builtin_amdgcn_mfma_f32_16x16x32_bf16(a, b1, a1, 0, 0, 0);
        }
        #pragma unroll
        for (int i = 0; i < 4; i++) {
            ybuf[ag_ * 4 + i][w * 32 + ar]      = a0[i];
            ybuf[ag_ * 4 + i][w * 32 + 16 + ar] = a1[i];
        }
    }
    __syncthreads();

    // phase 2+3 fused, per-wave: xres = x + rmsnorm(y)*anw; hs = rmsnorm(xres)*n2w
    #pragma unroll
    for (int i = 0; i < 4; i++) {
        int r = w * 4 + i;
        float y0 = ybuf[r][lane], y1 = ybuf[r][lane + 64];
        float s = wave_rsum(fmaf(y0, y0, y1 * y1));
        float sc = rsqrtf(s * (1.0f / 128.0f) + EPSF);
        const float* xp = x + (size_t)(r0 + r) * 128;
        float xr0 = xp[lane]      + y0 * sc * anw[lane];
        float xr1 = xp[lane + 64] + y1 * sc * anw[lane + 64];
        xres[r][lane] = xr0; xres[r][lane + 64] = xr1;
        float s2 = wave_rsum(fmaf(xr0, xr0, xr1 * xr1));
        float sc2 = rsqrtf(s2 * (1.0f / 128.0f) + EPSF);
        int p3 = (r & 7) << 3;
        hs[r * 128 + (lane ^ p3)]        = f2bs(xr0 * sc2 * n2w[lane]);
        hs[r * 128 + ((lane + 64) ^ p3)] = f2bs(xr1 * sc2 * n2w[lane + 64]);
    }
    __syncthreads();

    // phase 4: gu = silu(h2@gw)*(h2@uw)  (4 waves x 8 col-tiles)
    {
        const short* gwb = wsw + 65536;
        const short* uwb = wsw + 131072;
        bf16x8 af[4];
        #pragma unroll
        for (int ks = 0; ks < 4; ks++) af[ks] = lda(hs, lane, ks);
        f32x4 ag[8], au[8];
        #pragma unroll
        for (int i = 0; i < 8; i++) { ag[i] = (f32x4){0.f,0.f,0.f,0.f}; au[i] = (f32x4){0.f,0.f,0.f,0.f}; }
        #pragma unroll
        for (int ks = 0; ks < 4; ks++) {
            #pragma unroll
            for (int i = 0; i < 8; i++) {
                int ct = w * 8 + i;
                bf16x8 bg = *(const bf16x8*)(gwb + (((ct * 4 + ks) * 64 + lane) << 3));
                bf16x8 bu = *(const bf16x8*)(uwb + (((ct * 4 + ks) * 64 + lane) << 3));
                ag[i] = __builtin_amdgcn_mfma_f32_16x16x32_bf16(af[ks], bg, ag[i], 0, 0, 0);
                au[i] = __builtin_amdgcn_mfma_f32_16x16x32_bf16(af[ks], bu, au[i], 0, 0, 0);
            }
        }
        #pragma unroll
        for (int i = 0; i < 8; i++) {
            int col = (w * 8 + i) * 16 + ar;
            #pragma unroll
            for (int j = 0; j < 4; j++) {
                int row = ag_ * 4 + j;
                float g = ag[i][j], uu = au[i][j];
                float sg = g / (1.0f + __expf(-g));
                gu[row * 512 + (col ^ ((row & 7) << 3))] = f2bs(sg * uu);
            }
        }
    }
    __syncthreads();

    // phase 5: out = xres + gu @ dw (K=512)
    {
        const short* db = wsw + 196608;
        f32x4 a0 = {0.f,0.f,0.f,0.f}, a1 = {0.f,0.f,0.f,0.f};
        #pragma unroll
        for (int ks = 0; ks < 16; ks++) {
            int col = (ks * 32 + ag_ * 8) ^ ((ar & 7) << 3);
            bf16x8 a = *(const bf16x8*)(gu + ar * 512 + col);
            bf16x8 b0 = *(const bf16x8*)(db + ((((w * 2) * 16 + ks) * 64 + lane) << 3));
            bf16x8 b1 = *(const bf16x8*)(db + ((((w * 2 + 1) * 16 + ks) * 64 + lane) << 3));
            a0 = __builtin_amdgcn_mfma_f32_16x16x32_bf16(a, b0, a0, 0, 0, 0);
            a1 = __builtin_amdgcn_mfma_f32_16x16x32_bf16(a, b1, a1, 0, 0, 0);
        }
        #pragma unroll
        for (int i = 0; i < 4; i++) {
            int row = ag_ * 4 + i;
            size_t i0 = (size_t)(r0 + row) * 128 + w * 32 + ar;
            out[i0]      = xres[row][w * 32 + ar]      + a0[i];
            out[i0 + 16] = xres[row][w * 32 + 16 + ar] + a1[i];
        }
    }
}

extern "C" void kernel_launch(void* const* d_in, const int* in_sizes, int n_in,
                              void* d_out, int out_size, void* d_ws, size_t ws_size,
                              hipStream_t stream)
{
    const float* x   = (const float*)d_in[0];
    const float* n1  = (const float*)d_in[1];
    const float* anw = (const float*)d_in[2];
    const float* n2  = (const float*)d_in[3];
    const float* wq  = (const float*)d_in[4];
    const float* wk  = (const float*)d_in[5];
    const float* wv  = (const float*)d_in[6];
    const float* wo  = (const float*)d_in[7];
    const float* gw  = (const float*)d_in[8];
    const float* uw  = (const float*)d_in[9];
    const float* dw  = (const float*)d_in[10];
    float* out = (float*)d_out;

    float* ws = (float*)d_ws;
    short* qbf = (short*)ws;                   // 524288 shorts
    short* kbf = (short*)(ws + 262144);
    short* vbf = (short*)(ws + 524288);
    short* obf = (short*)(ws + 786432);
    short* wsw = (short*)(ws + 1048576);       // 262144 shorts

    k_prep<<<64,  512, 0, stream>>>(wq, wk, wv, wo, gw, uw, dw, wsw);
    k_qkv <<<256, 256, 0, stream>>>(x, n1, wsw, qbf, kbf, vbf);
    dim3 ga(128, 4);
    k_attn<<<ga,  256, 0, stream>>>(qbf, kbf, vbf, obf);
    k_post<<<256, 256, 0, stream>>>(obf, wsw, anw, x, n2, out);
}